// Round 1
// baseline (6205.155 us; speedup 1.0000x reference)
//
#include <hip/hip_runtime.h>
#include <cstdint>

typedef unsigned long long ull;

#define TILE_K 64

__device__ __forceinline__ unsigned f32_sortable(float f) {
  unsigned u = __float_as_uint(f);
  return (u & 0x80000000u) ? ~u : (u | 0x80000000u);
}

// ---------------------------------------------------------------------------
// Generic fp32 GEMM: C[m][n] = sum_k A[m][k] * B[k][n] (+bias)
// M-tile = 64 (grid.y), N-tile = 64 (grid.x), K split across grid.z chunks of Kc.
// GATHER: A rows are [emb[tok[m]] (512) | Hsrc[m] (1024)] (for the GRU gates GEMM).
// ARGMAX: per-row argmax over the whole N range via packed uint64 atomicMax.
// ---------------------------------------------------------------------------
template<bool GATHER, bool ARGMAX>
__global__ __launch_bounds__(256)
void gemm_kernel(const float* __restrict__ A, int lda,
                 const float* __restrict__ B, int ldb,
                 const float* __restrict__ bias,
                 float* __restrict__ C, long ldc, long zstride,
                 int Kc,
                 const float* __restrict__ emb,
                 const ull* __restrict__ tok_slot,
                 const float* __restrict__ Hsrc,
                 ull* __restrict__ amax)
{
  __shared__ float As[TILE_K][68];   // k-major, padded
  __shared__ float Bs[TILE_K][64];
  __shared__ int   stok[64];
  __shared__ ull   sbest[64];

  const int tid   = threadIdx.x;
  const int n0    = blockIdx.x << 6;
  const int m0    = blockIdx.y << 6;
  const int kbase = blockIdx.z * Kc;

  if (GATHER) {
    if (tid < 64) {
      int tk = 1; // BOS
      if (tok_slot) tk = (int)(0xFFFFFFFFu - (unsigned)(tok_slot[tid] & 0xFFFFFFFFull));
      stok[tid] = tk;
    }
  }
  if (ARGMAX) { if (tid < 64) sbest[tid] = 0ull; }

  float acc[4][4];
#pragma unroll
  for (int i = 0; i < 4; ++i)
#pragma unroll
    for (int j = 0; j < 4; ++j) acc[i][j] = 0.f;

  const int mg = tid >> 4;          // 0..15 (4 m each)
  const int nv = tid & 15;          // 0..15 (4 n each)
  const int arow_m = tid >> 2;      // 0..63
  const int akq    = (tid & 3) << 4;// 0,16,32,48

  for (int kt = 0; kt < Kc; kt += TILE_K) {
    __syncthreads();
    // ---- stage A (transposed to k-major) ----
#pragma unroll
    for (int j = 0; j < 4; ++j) {
      const int klocal = akq + (j << 2);
      const int kabs   = kbase + kt + klocal;
      const float* p;
      if (GATHER) {
        // 16-float segments are 16-aligned, never straddle the 512 boundary
        p = (kabs < 512) ? (emb + (size_t)stok[arow_m] * 512 + kabs)
                         : (Hsrc + (size_t)(m0 + arow_m) * 2048 + (kabs - 512));
      } else {
        p = A + (size_t)(m0 + arow_m) * lda + kabs;
      }
      float4 v = *(const float4*)p;
      As[klocal + 0][arow_m] = v.x;
      As[klocal + 1][arow_m] = v.y;
      As[klocal + 2][arow_m] = v.z;
      As[klocal + 3][arow_m] = v.w;
    }
    // ---- stage B ----
#pragma unroll
    for (int i = 0; i < 4; ++i) {
      int idx4 = tid + (i << 8);          // 0..1023 float4s
      int kl   = idx4 >> 4;
      int nn   = (idx4 & 15) << 2;
      float4 v = *(const float4*)(B + (size_t)(kbase + kt + kl) * ldb + (n0 + nn));
      *(float4*)&Bs[kl][nn] = v;
    }
    __syncthreads();
    // ---- compute ----
#pragma unroll 8
    for (int kl = 0; kl < TILE_K; ++kl) {
      float4 a4 = *(const float4*)&As[kl][mg << 2];
      float4 w4 = *(const float4*)&Bs[kl][nv << 2];
      acc[0][0] = fmaf(a4.x, w4.x, acc[0][0]);
      acc[0][1] = fmaf(a4.x, w4.y, acc[0][1]);
      acc[0][2] = fmaf(a4.x, w4.z, acc[0][2]);
      acc[0][3] = fmaf(a4.x, w4.w, acc[0][3]);
      acc[1][0] = fmaf(a4.y, w4.x, acc[1][0]);
      acc[1][1] = fmaf(a4.y, w4.y, acc[1][1]);
      acc[1][2] = fmaf(a4.y, w4.z, acc[1][2]);
      acc[1][3] = fmaf(a4.y, w4.w, acc[1][3]);
      acc[2][0] = fmaf(a4.z, w4.x, acc[2][0]);
      acc[2][1] = fmaf(a4.z, w4.y, acc[2][1]);
      acc[2][2] = fmaf(a4.z, w4.z, acc[2][2]);
      acc[2][3] = fmaf(a4.z, w4.w, acc[2][3]);
      acc[3][0] = fmaf(a4.w, w4.x, acc[3][0]);
      acc[3][1] = fmaf(a4.w, w4.y, acc[3][1]);
      acc[3][2] = fmaf(a4.w, w4.z, acc[3][2]);
      acc[3][3] = fmaf(a4.w, w4.w, acc[3][3]);
    }
  }

  // ---- epilogue ----
  float4 b4 = make_float4(0.f, 0.f, 0.f, 0.f);
  if (bias) b4 = *(const float4*)(bias + n0 + (nv << 2));
  float* Cz = C + (size_t)blockIdx.z * zstride;

#pragma unroll
  for (int i = 0; i < 4; ++i) {
    int m = m0 + (mg << 2) + i;
    float4 o;
    o.x = acc[i][0] + b4.x;
    o.y = acc[i][1] + b4.y;
    o.z = acc[i][2] + b4.z;
    o.w = acc[i][3] + b4.w;
    *(float4*)(Cz + (size_t)m * ldc + n0 + (nv << 2)) = o;
    if (ARGMAX) {
      int nb = n0 + (nv << 2);
      float bv = o.x; int bn = nb;
      if (o.y > bv) { bv = o.y; bn = nb + 1; }
      if (o.z > bv) { bv = o.z; bn = nb + 2; }
      if (o.w > bv) { bv = o.w; bn = nb + 3; }
      ull key = ((ull)f32_sortable(bv) << 32) | (ull)(0xFFFFFFFFu - (unsigned)bn);
      atomicMax(&sbest[(mg << 2) + i], key);
    }
  }
  if (ARGMAX) {
    __syncthreads();
    if (tid < 64) atomicMax(amax + tid, sbest[tid]);
  }
}

// ---------------------------------------------------------------------------
// GRU gate combine: h_new = (1-z)*n + z*h, from 8 k-split partials + bias6
// partials P: [8][64][4096]; cols: [r | z | inn | hn]
// ---------------------------------------------------------------------------
__global__ __launch_bounds__(256)
void combine_kernel(const float* __restrict__ P,
                    const float* __restrict__ bias6,
                    const float* __restrict__ hc_src,
                    float* __restrict__ hc_dst)
{
  int idx = blockIdx.x * 256 + threadIdx.x;  // 65536
  int b = idx >> 10, j = idx & 1023;
  float gr = bias6[j], gz = bias6[1024 + j], gn = bias6[2048 + j], gh = bias6[3072 + j];
  const float* p = P + (size_t)b * 4096;
#pragma unroll
  for (int z = 0; z < 8; ++z) {
    const float* q = p + (size_t)z * 262144;
    gr += q[j]; gz += q[1024 + j]; gn += q[2048 + j]; gh += q[3072 + j];
  }
  float r  = 1.f / (1.f + expf(-gr));
  float zz = 1.f / (1.f + expf(-gz));
  float n  = tanhf(gn + r * gh);
  float h  = hc_src[(size_t)b * 2048 + j];
  hc_dst[(size_t)b * 2048 + j] = (1.f - zz) * n + zz * h;
}

// ---------------------------------------------------------------------------
// Attention: scores = h_new . enc_wa[b,t,:], softmax over t, ctx into hc[b][1024..]
// ---------------------------------------------------------------------------
__global__ __launch_bounds__(256)
void attn_kernel(const float* __restrict__ enc,
                 const float* __restrict__ enc_wa,
                 float* __restrict__ hc)
{
  int b = blockIdx.x, tid = threadIdx.x;
  __shared__ float hq[1024];
  __shared__ float ps[64][4];
  __shared__ float attn_s[64];

  *(float4*)&hq[tid << 2] = *(const float4*)(hc + (size_t)b * 2048 + (tid << 2));
  __syncthreads();
  {
    int t = tid >> 2, part = tid & 3;
    const float* ew = enc_wa + ((size_t)b * 64 + t) * 1024 + part * 256;
    const float* hp = &hq[part * 256];
    float s = 0.f;
    for (int k = 0; k < 256; k += 4) {
      float4 v  = *(const float4*)(ew + k);
      float4 h4 = *(const float4*)(hp + k);
      s = fmaf(v.x, h4.x, s); s = fmaf(v.y, h4.y, s);
      s = fmaf(v.z, h4.z, s); s = fmaf(v.w, h4.w, s);
    }
    ps[t][part] = s;
  }
  __syncthreads();
  if (tid < 64) {
    float sc = ps[tid][0] + ps[tid][1] + ps[tid][2] + ps[tid][3];
    float m = sc;
#pragma unroll
    for (int off = 32; off; off >>= 1) m = fmaxf(m, __shfl_xor(m, off));
    float e = expf(sc - m);
    float su = e;
#pragma unroll
    for (int off = 32; off; off >>= 1) su += __shfl_xor(su, off);
    attn_s[tid] = e / su;
  }
  __syncthreads();
  float4 c = make_float4(0.f, 0.f, 0.f, 0.f);
  const float* eb = enc + (size_t)b * 65536;
#pragma unroll 4
  for (int t2 = 0; t2 < 64; ++t2) {
    float a = attn_s[t2];
    float4 v = *(const float4*)(eb + t2 * 1024 + (tid << 2));
    c.x = fmaf(a, v.x, c.x); c.y = fmaf(a, v.y, c.y);
    c.z = fmaf(a, v.z, c.z); c.w = fmaf(a, v.w, c.w);
  }
  *(float4*)(hc + (size_t)b * 2048 + 1024 + (tid << 2)) = c;
}

// ---------------------------------------------------------------------------
// Helpers: zero, transpose (out[c][r] = in[r][c]), misc setup
// ---------------------------------------------------------------------------
__global__ void zero_kernel(float4* p, int n4) {
  int i = blockIdx.x * 256 + threadIdx.x;
  if (i < n4) p[i] = make_float4(0.f, 0.f, 0.f, 0.f);
}

__global__ __launch_bounds__(256)
void transpose_kernel(const float* __restrict__ in, int ld_in,
                      float* __restrict__ out, int ld_out)
{
  __shared__ float t[32][33];
  int c0 = blockIdx.x << 5, r0 = blockIdx.y << 5;
  int tx = threadIdx.x & 31, ty = threadIdx.x >> 5;
#pragma unroll
  for (int i = 0; i < 32; i += 8)
    t[ty + i][tx] = in[(size_t)(r0 + ty + i) * ld_in + c0 + tx];
  __syncthreads();
#pragma unroll
  for (int i = 0; i < 32; i += 8)
    out[(size_t)(c0 + ty + i) * ld_out + r0 + tx] = t[tx][ty + i];
}

__global__ void setup_misc(const float* __restrict__ latent,
                           const int* __restrict__ style,
                           const float* __restrict__ style_emb,
                           const float* __restrict__ b_ih,
                           const float* __restrict__ b_hh,
                           float* __restrict__ latsty,
                           float* __restrict__ bias6,
                           ull* __restrict__ slots)
{
  int b = blockIdx.x, tid = threadIdx.x;
  if (tid < 192) {
    float v = (tid < 128) ? latent[b * 128 + tid]
                          : style_emb[style[b] * 64 + (tid - 128)];
    latsty[b * 192 + tid] = v;
  }
  if (b == 0) { for (int i = tid; i < 2048; i += 256) slots[i] = 0ull; }
  if (b >= 2 && b < 18) {
    int c = (b - 2) * 256 + tid;
    float v;
    if (c < 2048)      v = b_ih[c] + b_hh[c];
    else if (c < 3072) v = b_ih[c];
    else               v = b_hh[c - 1024];
    bias6[c] = v;
  }
}

// ---------------------------------------------------------------------------
extern "C" void kernel_launch(void* const* d_in, const int* in_sizes, int n_in,
                              void* d_out, int out_size, void* d_ws, size_t ws_size,
                              hipStream_t stream)
{
  const float* latent    = (const float*)d_in[0];
  const int*   style     = (const int*)  d_in[1];
  const float* enc       = (const float*)d_in[2];
  // d_in[3] = max_length (=32, fixed)
  const float* emb       = (const float*)d_in[4];
  const float* style_emb = (const float*)d_in[5];
  const float* W_l2h     = (const float*)d_in[6];
  const float* b_l2h     = (const float*)d_in[7];
  const float* W_ih      = (const float*)d_in[8];
  const float* W_hh      = (const float*)d_in[9];
  const float* b_ih      = (const float*)d_in[10];
  const float* b_hh      = (const float*)d_in[11];
  const float* W_a       = (const float*)d_in[12];
  const float* W_out     = (const float*)d_in[13];
  const float* b_out     = (const float*)d_in[14];
  float* out = (float*)d_out;

  float* ws       = (float*)d_ws;
  float* B_full   = ws;                       // [1536][4096] fused gate weights
  float* W_aT     = B_full + 6291456;         // [1024][1024]
  float* enc_wa   = W_aT + 1048576;           // [64][64][1024]
  float* hc0      = enc_wa + 4194304;         // [64][2048] (h | ctx)
  float* hc1      = hc0 + 131072;
  float* partials = hc1 + 131072;             // [8][64][4096]
  float* bias6    = partials + 2097152;       // [4096]
  float* latsty   = bias6 + 4096;             // [64][192]
  ull*   slots    = (ull*)(latsty + 12288);   // [32][64] argmax keys

  dim3 blk(256);

  // ---- setup ----
  zero_kernel<<<6144, blk, 0, stream>>>((float4*)B_full, 1572864);
  // B_full[k][j] = W_ih[j][k]  (k<512, j<3072)
  transpose_kernel<<<dim3(16, 96), blk, 0, stream>>>(W_ih, 512, B_full, 4096);
  // B_full[512+kh][j] = W_hh[j][kh] (j<2048)
  transpose_kernel<<<dim3(32, 64), blk, 0, stream>>>(W_hh, 1024, B_full + (size_t)512 * 4096, 4096);
  // B_full[512+kh][3072+j'] = W_hh[2048+j'][kh]
  transpose_kernel<<<dim3(32, 32), blk, 0, stream>>>(W_hh + (size_t)2048 * 1024, 1024,
                                                     B_full + (size_t)512 * 4096 + 3072, 4096);
  // W_aT[h][k] = W_a[k][h]
  transpose_kernel<<<dim3(32, 32), blk, 0, stream>>>(W_a, 1024, W_aT, 1024);
  setup_misc<<<64, blk, 0, stream>>>(latent, style, style_emb, b_ih, b_hh, latsty, bias6, slots);
  // h0 = latsty @ W_l2h + b_l2h -> hc0[:, 0:1024]
  gemm_kernel<false, false><<<dim3(16, 1, 1), blk, 0, stream>>>(
      latsty, 192, W_l2h, 1024, b_l2h, hc0, 2048L, 0L, 192,
      nullptr, nullptr, nullptr, nullptr);
  // enc_wa = enc @ W_a^T   (M=4096, N=1024, K=1024)
  gemm_kernel<false, false><<<dim3(16, 64, 1), blk, 0, stream>>>(
      enc, 1024, W_aT, 1024, nullptr, enc_wa, 1024L, 0L, 1024,
      nullptr, nullptr, nullptr, nullptr);

  // ---- 32 autoregressive steps ----
  for (int t = 0; t < 32; ++t) {
    float* src = (t & 1) ? hc1 : hc0;
    float* dst = (t & 1) ? hc0 : hc1;
    // gates6 = [x|h] @ B_full  (k-split 8 -> partials)
    gemm_kernel<true, false><<<dim3(64, 1, 8), blk, 0, stream>>>(
        nullptr, 0, B_full, 4096, nullptr, partials, 4096L, 262144L, 192,
        emb, t ? (slots + (t - 1) * 64) : (const ull*)nullptr, src, nullptr);
    combine_kernel<<<256, blk, 0, stream>>>(partials, bias6, src, dst);
    attn_kernel<<<64, blk, 0, stream>>>(enc, enc_wa, dst);
    // logits = [h_new|ctx] @ W_out + b_out  (+argmax into slots[t])
    gemm_kernel<false, true><<<dim3(500, 1, 1), blk, 0, stream>>>(
        dst, 2048, W_out, 32000, b_out, out + (size_t)t * 32000, 1024000L, 0L, 2048,
        nullptr, nullptr, nullptr, slots + t * 64);
  }
}